// Round 4
// baseline (166.224 us; speedup 1.0000x reference)
//
#include <hip/hip_runtime.h>
#include <math.h>

// ret[t] = r[t] + g*ret[t+1]; out = (ret-mean)/(std+eps).
// R4: wave-autonomous register-only scan. Each wave owns 2048 elems in
// column-major quad layout (8 rows x 256): lane l holds quad [256j+4l,+4).
// All global accesses coalesced dwordx4; scan = 6-level butterfly suffix scan
// per row with CONSTANT multipliers gamma^(4d); 1024-elem lookahead is a
// weighted reduction (err <= gamma^1024*|ret| ~ 1.4e-3 raw, way under thr).
// No LDS, no barriers, no inter-wave communication.

#define GAMMA 0.99f
#define EPSN  1e-4

constexpr int BLOCK  = 256;
constexpr int WPB    = BLOCK / 64;   // waves per block
constexpr int WCHUNK = 2048;         // elements per wave
constexpr int LAW    = 1024;         // lookahead elements per wave
constexpr int NACC   = 32;           // atomic slot pairs

__host__ __device__ constexpr float gpow(int k) {
  double p = 1.0;
  for (int i = 0; i < k; ++i) p *= 0.99;
  return (float)p;
}
constexpr float LOG2G = -0.014499569695f;   // log2(0.99)

__device__ __forceinline__ float4 load4g(const float* __restrict__ p, long long i, long long n) {
  if (i + 3 < n) return *reinterpret_cast<const float4*>(p + i);
  float4 v = make_float4(0.f, 0.f, 0.f, 0.f);   // beyond-end == semantic zero
  if (i < n)     v.x = p[i];
  if (i + 1 < n) v.y = p[i + 1];
  if (i + 2 < n) v.z = p[i + 2];
  return v;
}

__device__ __forceinline__ void store4g(float* __restrict__ p, long long i, long long n, float4 v) {
  if (i + 3 < n) { *reinterpret_cast<float4*>(p + i) = v; return; }
  if (i < n)     p[i] = v.x;
  if (i + 1 < n) p[i + 1] = v.y;
  if (i + 2 < n) p[i + 2] = v.z;
}

__global__ __launch_bounds__(BLOCK)
void scan_stats(const float* __restrict__ r, long long n,
                double* __restrict__ acc, float* __restrict__ out) {
  const int tid  = threadIdx.x;
  const int lane = tid & 63;
  const int wv   = tid >> 6;
  const long long gw = (long long)blockIdx.x * WPB + wv;   // global wave id
  const long long W  = gw * WCHUNK;
  if (W >= n) return;   // wave-uniform exit

  // guarded butterfly multipliers: gamma^(4d), 0 where lane+d would read OOB
  float gmul[6];
#pragma unroll
  for (int i = 0; i < 6; ++i) {
    const int d = 1 << i;
    gmul[i] = (lane + d < 64) ? gpow(4 << i) : 0.f;
  }
  const float w4     = exp2f((float)(4 * lane) * LOG2G);          // gamma^(4l)
  const float w4tail = exp2f((float)(4 * (63 - lane)) * LOG2G);   // gamma^(4(63-l))

  // ---- loads: 8 main quads + 4 lookahead quads, all coalesced ----
  float4 q[8], lq[4];
  const bool fast = (W + WCHUNK + LAW) <= n;
  if (fast) {
    const float4* p = reinterpret_cast<const float4*>(r + W) + lane;
#pragma unroll
    for (int j = 0; j < 8; ++j) q[j] = p[j * 64];
#pragma unroll
    for (int k = 0; k < 4; ++k) lq[k] = p[(8 + k) * 64];
  } else {
#pragma unroll
    for (int j = 0; j < 8; ++j) q[j] = load4g(r, W + 256 * j + 4 * lane, n);
#pragma unroll
    for (int k = 0; k < 4; ++k) lq[k] = load4g(r, W + WCHUNK + 256 * k + 4 * lane, n);
  }

  // per-quad suffix values: qsum = r0 + g r1 + g^2 r2 + g^3 r3
  float S[8], t[4];
#pragma unroll
  for (int j = 0; j < 8; ++j)
    S[j] = fmaf(GAMMA, fmaf(GAMMA, fmaf(GAMMA, q[j].w, q[j].z), q[j].y), q[j].x);
#pragma unroll
  for (int k = 0; k < 4; ++k) {
    const float v = fmaf(GAMMA, fmaf(GAMMA, fmaf(GAMMA, lq[k].w, lq[k].z), lq[k].y), lq[k].x);
    t[k] = v * w4;   // pre-weight -> reduction instead of scan
  }

  // ---- 6 butterfly levels: suffix scan (8 rows) + xor-sum (4 lookahead rows)
#pragma unroll
  for (int i = 0; i < 6; ++i) {
    const int d = 1 << i;
#pragma unroll
    for (int j = 0; j < 8; ++j) {
      const float u = __shfl_down(S[j], d);
      S[j] = fmaf(gmul[i], u, S[j]);
    }
#pragma unroll
    for (int k = 0; k < 4; ++k) t[k] += __shfl_xor(t[k], d);
  }

  // lookahead carry at W + WCHUNK
  constexpr float G256 = gpow(256);
  const float C = fmaf(G256, fmaf(G256, fmaf(G256, t[3], t[2]), t[1]), t[0]);

  // row carries: V[j] = value at start of row j+1 (i.e. beyond row j)
  float V[8];
  V[7] = C;
#pragma unroll
  for (int j = 6; j >= 0; --j)
    V[j] = fmaf(G256, V[j + 1], __shfl(S[j + 1], 0));   // rowtot = lane0 scan

  // ---- outputs + stats ----
  float sm = 0.f, sq = 0.f;
#pragma unroll
  for (int j = 0; j < 8; ++j) {
    const float Sn = __shfl_down(S[j], 1);              // suffix of lanes > l
    const float X  = fmaf(w4tail, V[j], (lane < 63) ? Sn : 0.f);
    const float o3 = fmaf(GAMMA, X,  q[j].w);
    const float o2 = fmaf(GAMMA, o3, q[j].z);
    const float o1 = fmaf(GAMMA, o2, q[j].y);
    const float o0 = fmaf(GAMMA, o1, q[j].x);
    sm += (o0 + o1) + (o2 + o3);
    sq = fmaf(o0, o0, sq); sq = fmaf(o1, o1, sq);
    sq = fmaf(o2, o2, sq); sq = fmaf(o3, o3, sq);
    q[j] = make_float4(o0, o1, o2, o3);
  }

  // coalesced stores (unnormalized returns)
  if (fast) {
    float4* po = reinterpret_cast<float4*>(out + W) + lane;
#pragma unroll
    for (int j = 0; j < 8; ++j) po[j * 64] = q[j];
  } else {
#pragma unroll
    for (int j = 0; j < 8; ++j) store4g(out, W + 256 * j + 4 * lane, n, q[j]);
  }

  // wave stats reduce -> spread double atomics
#pragma unroll
  for (int i = 0; i < 6; ++i) {
    const int d = 1 << i;
    sm += __shfl_down(sm, d);
    sq += __shfl_down(sq, d);
  }
  if (lane == 0) {
    const int slot = (int)(gw & (NACC - 1)) * 2;
    atomicAdd(&acc[slot], (double)sm);
    atomicAdd(&acc[slot + 1], (double)sq);
  }
}

// pure streaming normalize, in-place on out (L3-dirty data: near-free)
__global__ void k_norm(float* __restrict__ out, long long n, const float* __restrict__ mi) {
  const float m = mi[0], inv = mi[1];
  const long long n4 = n >> 2;
  float4* p = reinterpret_cast<float4*>(out);
  long long i = (long long)blockIdx.x * blockDim.x + threadIdx.x;
  const long long stride = (long long)gridDim.x * blockDim.x;
  for (; i < n4; i += stride) {
    float4 v = p[i];
    v.x = (v.x - m) * inv; v.y = (v.y - m) * inv;
    v.z = (v.z - m) * inv; v.w = (v.w - m) * inv;
    p[i] = v;
  }
  if (blockIdx.x == 0 && threadIdx.x == 0) {   // scalar tail (n % 4)
    for (long long tt = n4 << 2; tt < n; ++tt) out[tt] = (out[tt] - m) * inv;
  }
}

__global__ void k_zero(double* __restrict__ acc) {
  const int t = threadIdx.x;
  if (t < 2 * NACC) acc[t] = 0.0;
}

__global__ void k_finalize(const double* __restrict__ acc, long long n, float* __restrict__ mi) {
  double S = 0.0, Q = 0.0;
  for (int i = 0; i < NACC; ++i) { S += acc[2 * i]; Q += acc[2 * i + 1]; }
  double mean = S / (double)n;
  double var  = Q / (double)n - mean * mean;
  if (var < 0.0) var = 0.0;
  mi[0] = (float)mean;
  mi[1] = (float)(1.0 / (sqrt(var) + EPSN));
}

extern "C" void kernel_launch(void* const* d_in, const int* in_sizes, int n_in,
                              void* d_out, int out_size, void* d_ws, size_t ws_size,
                              hipStream_t stream) {
  const float* r = (const float*)d_in[0];
  float* out = (float*)d_out;
  const long long n = (long long)in_sizes[0];

  double* acc = (double*)d_ws;                   // 64 doubles = 512 B
  float*  mi  = (float*)((char*)d_ws + 512);     // mean, inv_std

  const long long nwaves = (n + WCHUNK - 1) / WCHUNK;   // 16384 for T=2^25
  const int nblk = (int)((nwaves + WPB - 1) / WPB);     // 4096

  k_zero<<<1, 64, 0, stream>>>(acc);
  scan_stats<<<nblk, BLOCK, 0, stream>>>(r, n, acc, out);
  k_finalize<<<1, 1, 0, stream>>>(acc, n, mi);
  k_norm<<<2048, BLOCK, 0, stream>>>(out, n, mi);
}